// Round 1
// baseline (865.440 us; speedup 1.0000x reference)
//
#include <hip/hip_runtime.h>

// ---------------- problem dims ----------------
#define T_DIM 256
#define B_DIM 512
#define D_DIM 128
#define H_DIM 128
#define A_DIM 8
#define N_ROWS (T_DIM*B_DIM)   // 131072 flattened rows
#define NT (N_ROWS/16)         // 8192 row tiles of 16

typedef __attribute__((ext_vector_type(4))) float f32x4;
typedef __attribute__((ext_vector_type(8))) short bf16x8;  // 8 bf16 in 4 VGPRs
typedef __attribute__((ext_vector_type(4))) short bf16x4;

// ---------------- workspace layout (bytes) ----------------
#define OFF_PSUM   0ull                    // 1024 blocks * 128 * f64 = 1 MB
#define OFF_PSQ    1048576ull              // 1 MB
#define OFF_STATM  2097152ull              // 128 f32
#define OFF_STATI  2097664ull              // 128 f32
#define OFF_WEMB   2098176ull              // 8ct  *4kb*64*8 bf16 = 32768 B
#define OFF_WI     2130944ull              // 24ct *...          = 98304 B
#define OFF_WHHI   2229248ull              // 98304 B
#define OFF_WHLO   2327552ull              // 98304 B
#define OFF_WACT   2425856ull              // 32768 B
#define OFF_WHEAD  2458624ull              // 1ct = 4096 B
#define OFF_XG     4194304ull              // NT*24*64*4 bf16 = 96 MB (C/D-frag order)
#define OFF_YS     104857600ull            // NT*8*64*4 bf16 = 32 MB (C/D-frag order)
// total ws need: 138412032 B (~132 MB)

// ---------------- output layout (f32 elements) ----------------
#define OUT_H      0          // h_last [512,128]
#define OUT_ALPHA  65536      // [256,512,8]
#define OUT_BETA   1114112    // [256,512,8]
#define OUT_M      2162688    // [128]
#define OUT_S      2162816    // [128]

__device__ inline short f2bf(float x){              // round-to-nearest-even f32->bf16
  union { float f; unsigned u; } v; v.f = x;
  unsigned r = v.u + 0x7FFFu + ((v.u>>16)&1u);
  return (short)(r>>16);
}
__device__ inline float bf2f(short h){
  union { unsigned u; float f; } v; v.u = ((unsigned)(unsigned short)h)<<16; return v.f;
}
__device__ inline float sigm(float x){ return 1.f/(1.f+expf(-x)); }

// ============ K1: per-column partial sum / sumsq over obs rows ============
__global__ __launch_bounds__(256) void k_partial(const float* __restrict__ obs,
                                                 double* __restrict__ psum,
                                                 double* __restrict__ psq){
  int tid = threadIdx.x; int col = tid & 127; int rh = tid >> 7;
  double s = 0.0, q = 0.0;
  for (int r = blockIdx.x*2 + rh; r < N_ROWS; r += 2048){
    float v = obs[(size_t)r*D_DIM + col];
    s += (double)v; q += (double)v*(double)v;
  }
  __shared__ double ls[256], lq[256];
  ls[tid]=s; lq[tid]=q; __syncthreads();
  if (rh==0){
    psum[(size_t)blockIdx.x*128 + col] = ls[tid] + ls[tid+128];
    psq [(size_t)blockIdx.x*128 + col] = lq[tid] + lq[tid+128];
  }
}

// ============ K2: finalize Welford (chunk-combine), write M,S + norm stats ============
__global__ __launch_bounds__(1024) void k_stats(const double* __restrict__ psum,
                                                const double* __restrict__ psq,
                                                const float* __restrict__ mean_obs,
                                                const float* __restrict__ welfS,
                                                const int* __restrict__ runcnt,
                                                float* __restrict__ outM, float* __restrict__ outS,
                                                float* __restrict__ wsM,  float* __restrict__ wsI){
  int tid = threadIdx.x; int col = tid & 127; int seg = tid >> 7; // 8 segs
  double s=0.0, q=0.0;
  for (int b=seg; b<1024; b+=8){ s += psum[(size_t)b*128+col]; q += psq[(size_t)b*128+col]; }
  __shared__ double ls[1024], lq[1024];
  ls[tid]=s; lq[tid]=q; __syncthreads();
  if (seg==0){
    for (int b=1;b<8;b++){ s += ls[b*128+col]; q += lq[b*128+col]; }
    double c0 = (double)runcnt[0];
    double Nn = (double)N_ROWS;
    double n  = c0 + Nn;
    double M0 = (double)mean_obs[col], S0 = (double)welfS[col];
    double mb = s / Nn;
    double delta = mb - M0;
    double M = M0 + delta * Nn / n;
    double M2b = q - Nn*mb*mb;
    double S = S0 + M2b + delta*delta*c0*Nn/n;
    double var = S / (n - 1.0);
    float inv = (float)(1.0/(sqrt(var)+1e-8));
    outM[col] = (float)M; outS[col] = (float)S;
    wsM[col]  = (float)M; wsI[col]  = inv;
  }
}

// ============ K3: pack weights into MFMA B-fragment order ============
// layout: ((ct*4+kb)*64+lane)*8+j  holds  W[k= kb*32+(lane>>4)*8+j][n= ct*16+(lane&15)]
// mode 0: bf16(w)   mode 1: hi=bf16(w)   mode 2: lo=bf16(w - f32(hi))
__global__ void k_pack(const float* __restrict__ src, short* __restrict__ dst,
                       int C, int total, int mode){
  int idx = blockIdx.x*256 + threadIdx.x;
  if (idx >= total) return;
  int j = idx & 7, lane = (idx>>3)&63, kb = (idx>>9)&3, ct = idx>>11;
  int k = kb*32 + (lane>>4)*8 + j;
  int n = ct*16 + (lane&15);
  float w = src[(size_t)k*C + n];
  short h = f2bf(w);
  if (mode==2) h = f2bf(w - bf2f(h));
  dst[idx] = h;
}
__global__ void k_pack_head(const float* __restrict__ wa, const float* __restrict__ wb,
                            short* __restrict__ dst){
  int idx = blockIdx.x*256 + threadIdx.x;
  if (idx >= 2048) return;
  int j = idx & 7, lane = (idx>>3)&63, kb = (idx>>9)&3;
  int k = kb*32 + (lane>>4)*8 + j;
  int n = lane & 15;
  float w = (n<8) ? wa[(size_t)k*8 + n] : wb[(size_t)k*8 + (n-8)];
  dst[idx] = f2bf(w);
}

// ============ K4: fused normalize -> emb(MFMA) -> relu -> xg(MFMA) ============
// one wave per 16-row tile; xg stored in C/D-frag order for direct GRU consumption
__global__ __launch_bounds__(256) void k_embxg(const float* __restrict__ obs,
                                               const float* __restrict__ wsM,
                                               const float* __restrict__ wsI,
                                               const short* __restrict__ Bemb,
                                               const float* __restrict__ b_emb,
                                               const short* __restrict__ BWi,
                                               short* __restrict__ xgpk){
  int tid=threadIdx.x, w=tid>>6, lane=tid&63, q=lane>>4, l=lane&15;
  int rt = blockIdx.x*4 + w;          // row tile (16 rows)
  int r0 = rt*16;
  __shared__ short embLds[4][16][136];   // +8 shorts pad; 272B row stride keeps b128 16B-aligned

  // --- A fragments: normalized obs, bf16 ---
  bf16x8 A[4];
  #pragma unroll
  for (int kb=0; kb<4; kb++){
    int k0 = kb*32 + q*8;
    const f32x4* po = (const f32x4*)(obs + (size_t)(r0+l)*D_DIM + k0);
    f32x4 o0 = po[0], o1 = po[1];
    const f32x4* pm = (const f32x4*)(wsM + k0);
    const f32x4* pi = (const f32x4*)(wsI + k0);
    f32x4 m0 = pm[0], m1 = pm[1], i0 = pi[0], i1 = pi[1];
    bf16x8 a;
    a[0]=f2bf((o0[0]-m0[0])*i0[0]); a[1]=f2bf((o0[1]-m0[1])*i0[1]);
    a[2]=f2bf((o0[2]-m0[2])*i0[2]); a[3]=f2bf((o0[3]-m0[3])*i0[3]);
    a[4]=f2bf((o1[0]-m1[0])*i1[0]); a[5]=f2bf((o1[1]-m1[1])*i1[1]);
    a[6]=f2bf((o1[2]-m1[2])*i1[2]); a[7]=f2bf((o1[3]-m1[3])*i1[3]);
    A[kb]=a;
  }
  // --- emb = relu(obs_n @ W_emb + b) ---
  const bf16x8* BE = (const bf16x8*)Bemb;
  f32x4 accE[8];
  #pragma unroll
  for (int ct=0; ct<8; ct++){ f32x4 z = {0.f,0.f,0.f,0.f}; accE[ct]=z; }
  #pragma unroll
  for (int ct=0; ct<8; ct++)
    #pragma unroll
    for (int kb=0; kb<4; kb++)
      accE[ct] = __builtin_amdgcn_mfma_f32_16x16x32_bf16(A[kb], BE[(ct*4+kb)*64+lane], accE[ct], 0,0,0);
  #pragma unroll
  for (int ct=0; ct<8; ct++){
    int col = ct*16 + l;
    float bb = b_emb[col];
    #pragma unroll
    for (int r2=0;r2<4;r2++){
      float e = accE[ct][r2] + bb; e = e>0.f ? e : 0.f;
      embLds[w][q*4+r2][col] = f2bf(e);     // C/D layout -> A layout via LDS
    }
  }
  __syncthreads();
  bf16x8 A2[4];
  #pragma unroll
  for (int kb=0;kb<4;kb++) A2[kb] = *(const bf16x8*)&embLds[w][l][kb*32+q*8];
  // --- xg = emb @ Wi (no bias) ---
  const bf16x8* BW = (const bf16x8*)BWi;
  f32x4 accX[24];
  #pragma unroll
  for (int ct=0;ct<24;ct++){ f32x4 z = {0.f,0.f,0.f,0.f}; accX[ct]=z; }
  #pragma unroll
  for (int ct=0;ct<24;ct++)
    #pragma unroll
    for (int kb=0;kb<4;kb++)
      accX[ct] = __builtin_amdgcn_mfma_f32_16x16x32_bf16(A2[kb], BW[(ct*4+kb)*64+lane], accX[ct], 0,0,0);
  bf16x4* xg4 = (bf16x4*)xgpk;
  #pragma unroll
  for (int ct=0;ct<24;ct++){
    bf16x4 v;
    v[0]=f2bf(accX[ct][0]); v[1]=f2bf(accX[ct][1]);
    v[2]=f2bf(accX[ct][2]); v[3]=f2bf(accX[ct][3]);
    xg4[((size_t)rt*24+ct)*64 + lane] = v;   // packed C/D-frag order
  }
}

// ============ K5: GRU scan. 32 blocks x 512 thr; wave w owns h cols [16w,16w+16) ============
// hg = h@Wh via 3-term bf16 split (~f32 precision); one barrier/step; Wh frags live in VGPRs.
__global__ __launch_bounds__(512) void k_gru(const float* __restrict__ hidden,
                                             const unsigned char* __restrict__ dones,
                                             const short* __restrict__ xgpk,
                                             const short* __restrict__ Whhi,
                                             const short* __restrict__ Whlo,
                                             const float* __restrict__ bh,
                                             short* __restrict__ yspk,
                                             float* __restrict__ h_last){
  int tid=threadIdx.x, w=tid>>6, lane=tid&63, q=lane>>4, l=lane&15;
  int b0 = blockIdx.x*16;
  __shared__ short hHi[2][16][136];
  __shared__ short hLo[2][16][136];

  bf16x8 BH[3][4], BL[3][4];                  // 96 VGPRs, loaded once
  const bf16x8* ph = (const bf16x8*)Whhi;
  const bf16x8* pl = (const bf16x8*)Whlo;
  #pragma unroll
  for (int g=0; g<3; g++)
    #pragma unroll
    for (int kb=0; kb<4; kb++){
      int ct = g*8 + w;
      BH[g][kb] = ph[(ct*4+kb)*64+lane];
      BL[g][kb] = pl[(ct*4+kb)*64+lane];
    }
  float bhv[3];
  #pragma unroll
  for (int g=0;g<3;g++) bhv[g] = bh[g*128 + w*16 + l];
  float hv[4];
  #pragma unroll
  for (int r2=0;r2<4;r2++) hv[r2] = hidden[(size_t)(b0 + q*4 + r2)*H_DIM + w*16 + l];

  const bf16x4* xg4 = (const bf16x4*)xgpk;
  bf16x4* ys4 = (bf16x4*)yspk;

  for (int t=0; t<T_DIM; t++){
    int buf = t & 1;
    #pragma unroll
    for (int r2=0;r2<4;r2++){
      if (dones[(size_t)t*B_DIM + b0 + q*4 + r2]) hv[r2] = 0.f;   // reset before use
      short hi = f2bf(hv[r2]);
      short lo = f2bf(hv[r2] - bf2f(hi));
      hHi[buf][q*4+r2][w*16+l] = hi;
      hLo[buf][q*4+r2][w*16+l] = lo;
    }
    __syncthreads();
    bf16x8 Ah[4], Al[4];
    #pragma unroll
    for (int kb=0;kb<4;kb++){
      Ah[kb] = *(const bf16x8*)&hHi[buf][l][kb*32+q*8];
      Al[kb] = *(const bf16x8*)&hLo[buf][l][kb*32+q*8];
    }
    f32x4 acc[3];
    #pragma unroll
    for (int g=0;g<3;g++){
      f32x4 a = {0.f,0.f,0.f,0.f};
      #pragma unroll
      for (int kb=0;kb<4;kb++){
        a = __builtin_amdgcn_mfma_f32_16x16x32_bf16(Ah[kb], BH[g][kb], a, 0,0,0);
        a = __builtin_amdgcn_mfma_f32_16x16x32_bf16(Ah[kb], BL[g][kb], a, 0,0,0);
        a = __builtin_amdgcn_mfma_f32_16x16x32_bf16(Al[kb], BH[g][kb], a, 0,0,0);
      }
      acc[g]=a;
    }
    size_t tile = (size_t)t*32 + blockIdx.x;
    bf16x4 xr4 = xg4[(tile*24 +      w)*64 + lane];
    bf16x4 xz4 = xg4[(tile*24 +  8 + w)*64 + lane];
    bf16x4 xn4 = xg4[(tile*24 + 16 + w)*64 + lane];
    bf16x4 yv;
    #pragma unroll
    for (int r2=0;r2<4;r2++){
      float rg = sigm(bf2f(xr4[r2]) + acc[0][r2] + bhv[0]);
      float zg = sigm(bf2f(xz4[r2]) + acc[1][r2] + bhv[1]);
      float ng = tanhf(bf2f(xn4[r2]) + rg*(acc[2][r2] + bhv[2]));
      hv[r2] = (1.f - zg)*ng + zg*hv[r2];
      yv[r2] = f2bf(hv[r2]);
    }
    ys4[(tile*8 + w)*64 + lane] = yv;
  }
  #pragma unroll
  for (int r2=0;r2<4;r2++)
    h_last[(size_t)(b0+q*4+r2)*H_DIM + w*16 + l] = hv[r2];
}

// ============ K6: act = relu(ys@W_act+b); alpha/beta = softplus(act@W+b)+1 ============
__global__ __launch_bounds__(256) void k_heads(const short* __restrict__ yspk,
                                               const short* __restrict__ Bact,
                                               const float* __restrict__ b_act,
                                               const short* __restrict__ Bhead,
                                               const float* __restrict__ b_alpha,
                                               const float* __restrict__ b_beta,
                                               float* __restrict__ alpha,
                                               float* __restrict__ beta){
  int tid=threadIdx.x, w=tid>>6, lane=tid&63, q=lane>>4, l=lane&15;
  size_t rt = (size_t)blockIdx.x*4 + w;
  __shared__ short tl[4][16][136];
  const bf16x4* ys4 = (const bf16x4*)yspk;
  #pragma unroll
  for (int ct=0; ct<8; ct++){
    bf16x4 v = ys4[(rt*8+ct)*64+lane];
    #pragma unroll
    for (int r2=0;r2<4;r2++) tl[w][q*4+r2][ct*16+l] = v[r2];
  }
  __syncthreads();
  bf16x8 A[4];
  #pragma unroll
  for (int kb=0;kb<4;kb++) A[kb] = *(const bf16x8*)&tl[w][l][kb*32+q*8];
  __syncthreads();                                  // WAR before act overwrite
  const bf16x8* BA = (const bf16x8*)Bact;
  f32x4 accA[8];
  #pragma unroll
  for (int ct=0;ct<8;ct++){ f32x4 z = {0.f,0.f,0.f,0.f}; accA[ct]=z; }
  #pragma unroll
  for (int ct=0;ct<8;ct++)
    #pragma unroll
    for (int kb=0;kb<4;kb++)
      accA[ct] = __builtin_amdgcn_mfma_f32_16x16x32_bf16(A[kb], BA[(ct*4+kb)*64+lane], accA[ct], 0,0,0);
  #pragma unroll
  for (int ct=0;ct<8;ct++){
    int col = ct*16 + l;
    float bb = b_act[col];
    #pragma unroll
    for (int r2=0;r2<4;r2++){
      float e = accA[ct][r2] + bb; e = e>0.f ? e : 0.f;
      tl[w][q*4+r2][col] = f2bf(e);
    }
  }
  __syncthreads();
  bf16x8 A2[4];
  #pragma unroll
  for (int kb=0;kb<4;kb++) A2[kb] = *(const bf16x8*)&tl[w][l][kb*32+q*8];
  const bf16x8* BHd = (const bf16x8*)Bhead;
  f32x4 acc = {0.f,0.f,0.f,0.f};
  #pragma unroll
  for (int kb=0;kb<4;kb++)
    acc = __builtin_amdgcn_mfma_f32_16x16x32_bf16(A2[kb], BHd[kb*64+lane], acc, 0,0,0);
  float bb = (l<8) ? b_alpha[l] : b_beta[l-8];
  float* dst = (l<8) ? alpha : beta;
  int cc = (l<8) ? l : l-8;
  #pragma unroll
  for (int r2=0;r2<4;r2++){
    float u = acc[r2] + bb;
    float sp = fmaxf(u,0.f) + log1pf(expf(-fabsf(u)));   // stable softplus
    dst[(rt*16 + q*4 + r2)*8 + cc] = sp + 1.f;
  }
}

// ================= host launcher =================
extern "C" void kernel_launch(void* const* d_in, const int* in_sizes, int n_in,
                              void* d_out, int out_size, void* d_ws, size_t ws_size,
                              hipStream_t stream){
  const float* hidden   = (const float*)d_in[0];
  const float* obs      = (const float*)d_in[1];
  const unsigned char* dones = (const unsigned char*)d_in[2];  // jnp bool = 1 byte
  const float* mean_obs = (const float*)d_in[3];
  const float* welfS    = (const float*)d_in[4];
  const int*   runcnt   = (const int*)d_in[5];
  const float* W_emb = (const float*)d_in[6];
  const float* b_emb = (const float*)d_in[7];
  const float* Wi    = (const float*)d_in[8];
  const float* Wh    = (const float*)d_in[9];
  const float* bh    = (const float*)d_in[10];
  const float* W_act = (const float*)d_in[11];
  const float* b_act = (const float*)d_in[12];
  const float* W_al  = (const float*)d_in[13];
  const float* b_al  = (const float*)d_in[14];
  const float* W_be  = (const float*)d_in[15];
  const float* b_be  = (const float*)d_in[16];
  float* out = (float*)d_out;
  char*  ws  = (char*)d_ws;

  double* psum = (double*)(ws + OFF_PSUM);
  double* psq  = (double*)(ws + OFF_PSQ);
  float*  wsM  = (float*)(ws + OFF_STATM);
  float*  wsI  = (float*)(ws + OFF_STATI);
  short*  Bemb = (short*)(ws + OFF_WEMB);
  short*  BWi  = (short*)(ws + OFF_WI);
  short*  BWhh = (short*)(ws + OFF_WHHI);
  short*  BWhl = (short*)(ws + OFF_WHLO);
  short*  Bact = (short*)(ws + OFF_WACT);
  short*  Bhead= (short*)(ws + OFF_WHEAD);
  short*  xgpk = (short*)(ws + OFF_XG);
  short*  yspk = (short*)(ws + OFF_YS);

  k_partial<<<1024,256,0,stream>>>(obs, psum, psq);
  k_stats<<<1,1024,0,stream>>>(psum, psq, mean_obs, welfS, runcnt,
                               out+OUT_M, out+OUT_S, wsM, wsI);
  k_pack<<<64, 256,0,stream>>>(W_emb, Bemb, 128, 16384, 0);
  k_pack<<<192,256,0,stream>>>(Wi,    BWi,  384, 49152, 0);
  k_pack<<<192,256,0,stream>>>(Wh,    BWhh, 384, 49152, 1);
  k_pack<<<192,256,0,stream>>>(Wh,    BWhl, 384, 49152, 2);
  k_pack<<<64, 256,0,stream>>>(W_act, Bact, 128, 16384, 0);
  k_pack_head<<<8,256,0,stream>>>(W_al, W_be, Bhead);
  k_embxg<<<2048,256,0,stream>>>(obs, wsM, wsI, Bemb, b_emb, BWi, xgpk);
  k_gru<<<32,512,0,stream>>>(hidden, dones, xgpk, BWhh, BWhl, bh, yspk, out + OUT_H);
  k_heads<<<2048,256,0,stream>>>(yspk, Bact, b_act, Bhead, b_al, b_be,
                                 out + OUT_ALPHA, out + OUT_BETA);
}